// Round 9
// baseline (26.452 us; speedup 1.0000x reference)
//
#include <hip/hip_runtime.h>
#include <hip/hip_bf16.h>

#define D 128
#define Nn 512
#define Bb 2

typedef __bf16 bf16x8_t __attribute__((ext_vector_type(8)));
typedef unsigned short u16x8_t __attribute__((ext_vector_type(8)));
typedef float f32x4_t __attribute__((ext_vector_type(4)));
typedef float f32x8_t __attribute__((ext_vector_type(8)));

// ---------------------------------------------------------------------------
// Kernel 1: A16[b,i,e] = bf16((dom*evo)@W1[:D] + b1); C16[b,i,e] = bf16((dom*evo)@W1[D:])
// 2 rows per block (512 blocks), W1 column stream shared 2-ways.
// Blocks 0..7 additionally emit W2T[e][k] = bf16(W2[k][e])  (64 x 128, 16 KB).
// ---------------------------------------------------------------------------
__global__ __launch_bounds__(256)
void precompute_ac(const float* __restrict__ dom, const float* __restrict__ evo,
                   const float* __restrict__ W1, const float* __restrict__ b1,
                   const float* __restrict__ W2,
                   __bf16* __restrict__ A16, __bf16* __restrict__ C16,
                   __bf16* __restrict__ W2T) {
    const int t = threadIdx.x;
    const int base = blockIdx.x * 2;
    if (blockIdx.x < 8) {
#pragma unroll
        for (int z = 0; z < 4; ++z) {
            int idx = z * 256 + t;                 // 0..1023
            int e = blockIdx.x * 8 + (idx >> 7);   // 8 e-rows per block
            int k = idx & 127;
            W2T[e * 128 + k] = (__bf16)W2[k * 64 + e];
        }
    }
    __shared__ float g2[2][D];
    {
        int r = t >> 7, c = t & 127;
        size_t off = (size_t)(base + r) * D + c;
        g2[r][c] = dom[off] * evo[off];
    }
    __syncthreads();
    const int half = t >> 7;                       // 0 -> A, 1 -> C
    const int e = t & 127;
    const float* Wp = W1 + half * D * D;
    float a0 = 0.f, a1 = 0.f;
#pragma unroll 16
    for (int dp = 0; dp < D; ++dp) {
        float w = Wp[dp * D + e];
        a0 = fmaf(g2[0][dp], w, a0);
        a1 = fmaf(g2[1][dp], w, a1);
    }
    if (half == 0) {
        float bb = b1[e];
        A16[(size_t)(base + 0) * D + e] = (__bf16)(a0 + bb);
        A16[(size_t)(base + 1) * D + e] = (__bf16)(a1 + bb);
    } else {
        C16[(size_t)(base + 0) * D + e] = (__bf16)a0;
        C16[(size_t)(base + 1) * D + e] = (__bf16)a1;
    }
}

// sum across each 16-lane row via DPP row_shr; FULL SUM LANDS IN ROW-LANE 15.
__device__ __forceinline__ float row16_reduce(float x) {
    int v = __builtin_bit_cast(int, x);
    x += __builtin_bit_cast(float, __builtin_amdgcn_update_dpp(0, v, 0x118, 0xf, 0xf, false));
    v = __builtin_bit_cast(int, x);
    x += __builtin_bit_cast(float, __builtin_amdgcn_update_dpp(0, v, 0x114, 0xf, 0xf, false));
    v = __builtin_bit_cast(int, x);
    x += __builtin_bit_cast(float, __builtin_amdgcn_update_dpp(0, v, 0x112, 0xf, 0xf, false));
    v = __builtin_bit_cast(int, x);
    x += __builtin_bit_cast(float, __builtin_amdgcn_update_dpp(0, v, 0x111, 0xf, 0xf, false));
    return x;
}

// ---------------------------------------------------------------------------
// Kernel 2: grid = the 1152 active (b, i-group-4, j-chunk-64) units, dispatched
// HEAVY-FIRST (u reversed).  4 waves, wave = one i.  C-fragments read straight
// from L2/LLC with a 1-deep cross-jt double buffer (loads for jt+1 issued
// before computing jt).  LDS = W2T (16 KB swizzled) + tile (1 KB).
// __launch_bounds__(256,4): 128-VGPR cap, live set ~120 -> NO scratch spill,
// 4 blocks/CU.  DPP row-reduce (m==15), sigmoid; upper rows coalesced, lower
// mirror as 16B column segments. Diagonal = 0.
// ---------------------------------------------------------------------------
__global__ __launch_bounds__(256, 4)
void coevo_main(const __bf16* __restrict__ A16, const __bf16* __restrict__ Cm,
                const __bf16* __restrict__ W2T, const float* __restrict__ b2,
                const float* __restrict__ W3, const float* __restrict__ b3,
                float* __restrict__ out) {
    const int tid  = threadIdx.x;
    const int wave = tid >> 6;
    const int lane = tid & 63;
    const int m = lane & 15;
    const int q = lane >> 4;

    int uu = blockIdx.x;
    const int b = (uu >= 576) ? 1 : 0;
    uu -= b * 576;
    const int u = 575 - uu;                        // heavy chunks dispatch first
    int chunk = 0;
#pragma unroll
    for (int cc = 1; cc < 8; ++cc) if (u >= 8 * cc * (cc + 1)) chunk = cc;
    const int g = u - 8 * chunk * (chunk + 1);     // 0 .. 16*(chunk+1)-1
    const int i = g * 4 + wave;
    const int i0 = g * 4;

    __shared__ __bf16 w2s[64 * 128];               // 16 KB, swizzled
    __shared__ float  tile[4][64];                 // block output tile

    // ---- A row (bf16, b1 folded): 4 x 16B loads, issued first
    const u16x8_t* Ag8 = (const u16x8_t*)(A16 + ((size_t)(b * Nn + i)) * D);
    u16x8_t ab16[4];
#pragma unroll
    for (int kk = 0; kk < 4; ++kk) ab16[kk] = Ag8[kk * 4 + q];

    // ---- stage W2T into LDS: 1024 granules of 16B, 4 per thread, swizzled
    {
        f32x4_t* w2v = (f32x4_t*)w2s;
        const f32x4_t* W2Tg = (const f32x4_t*)W2T;
#pragma unroll
        for (int it = 0; it < 4; ++it) {
            int f = it * 256 + tid;
            int r = f >> 4, gi = f & 15;
            w2v[r * 16 + (gi ^ (r & 15))] = W2Tg[f];
        }
    }

    // ---- expand A to f32 once (32 VGPR)
    f32x8_t abv[4];
#pragma unroll
    for (int kk = 0; kk < 4; ++kk) {
#pragma unroll
        for (int z = 0; z < 8; ++z)
            abv[kk][z] = __builtin_bit_cast(float, (unsigned)ab16[kk][z] << 16);
    }

    // ---- epilogue constants for this lane's columns e = et*16 + m
    float b2v[4], w3v[4];
#pragma unroll
    for (int et = 0; et < 4; ++et) {
        b2v[et] = b2[et * 16 + m];
        w3v[et] = W3[et * 16 + m];
    }
    const float b3s = b3[0];

    const u16x8_t* Cg8 = (const u16x8_t*)(Cm + ((size_t)b * Nn + (size_t)chunk * 64) * D);

    // ---- preload jt=0 C fragments (before the barrier: pure global)
    u16x8_t cr[2][4];
#pragma unroll
    for (int kk = 0; kk < 4; ++kk) cr[0][kk] = Cg8[m * 16 + kk * 4 + q];

    __syncthreads();

    const bf16x8_t* w2r = (const bf16x8_t*)w2s;

#pragma unroll
    for (int jt = 0; jt < 4; ++jt) {
        // ---- prefetch next jt's C fragments (always valid addresses)
        if (jt < 3) {
            const int rn = (jt + 1) * 16 + m;
#pragma unroll
            for (int kk = 0; kk < 4; ++kk)
                cr[(jt + 1) & 1][kk] = Cg8[rn * 16 + kk * 4 + q];
        }
        if (chunk * 64 + jt * 16 + 15 >= i) {      // tile not fully below diag
            // ---- build H fragments: h = relu(a + c)
            bf16x8_t af[4];
#pragma unroll
            for (int kk = 0; kk < 4; ++kk) {
                u16x8_t c16 = cr[jt & 1][kk];
                f32x8_t c8;
#pragma unroll
                for (int z = 0; z < 8; ++z)
                    c8[z] = __builtin_bit_cast(float, (unsigned)c16[z] << 16);
                f32x8_t t8 = __builtin_elementwise_max(abv[kk] + c8, (f32x8_t)0.f);
                af[kk] = __builtin_convertvector(t8, bf16x8_t);
            }

            // ---- GEMM + epilogue fused per et (acc stays at 4 VGPR)
            float part[4] = {0.f, 0.f, 0.f, 0.f};
#pragma unroll
            for (int et = 0; et < 4; ++et) {
                bf16x8_t wf[4];
#pragma unroll
                for (int kk = 0; kk < 4; ++kk)
                    wf[kk] = w2r[(et * 16 + m) * 16 + ((kk * 4 + q) ^ m)];
                f32x4_t a = {0.f, 0.f, 0.f, 0.f};
#pragma unroll
                for (int kk = 0; kk < 4; ++kk)
                    a = __builtin_amdgcn_mfma_f32_16x16x32_bf16(af[kk], wf[kk], a, 0, 0, 0);
#pragma unroll
                for (int r = 0; r < 4; ++r)
                    part[r] = fmaf(fmaxf(a[r] + b2v[et], 0.f), w3v[et], part[r]);
            }

            // ---- DPP reduce over 16 e-lanes (result in m==15), sigmoid, park
            float red[4];
#pragma unroll
            for (int r = 0; r < 4; ++r) red[r] = row16_reduce(part[r]);
            if (m == 15) {
#pragma unroll
                for (int r = 0; r < 4; ++r) {
                    int jc = jt * 16 + q * 4 + r;
                    tile[wave][jc] = 1.f / (1.f + expf(-(red[r] + b3s)));
                }
            }
        }
    }

    __syncthreads();

    // ---- upper store: row i, 64 cols (coalesced f32x4), diag = 0
    if ((tid & 63) < 16) {
        const int c4 = tid & 15;
        const int j0 = chunk * 64 + c4 * 4;
        float v0 = tile[wave][c4 * 4 + 0];
        float v1 = tile[wave][c4 * 4 + 1];
        float v2 = tile[wave][c4 * 4 + 2];
        float v3 = tile[wave][c4 * 4 + 3];
        float* op = out + ((size_t)b * Nn + i) * Nn + j0;
        if (j0 > i) {
            f32x4_t v; v[0] = v0; v[1] = v1; v[2] = v2; v[3] = v3;
            *(f32x4_t*)op = v;
        } else if (j0 + 3 >= i) {                  // straddles diagonal
            if (j0 + 0 > i) op[0] = v0; else if (j0 + 0 == i) op[0] = 0.f;
            if (j0 + 1 > i) op[1] = v1; else if (j0 + 1 == i) op[1] = 0.f;
            if (j0 + 2 > i) op[2] = v2; else if (j0 + 2 == i) op[2] = 0.f;
            if (j0 + 3 > i) op[3] = v3; else if (j0 + 3 == i) op[3] = 0.f;
        }                                          // else fully below diag: skip
    }
    // ---- lower (mirror) store: 64 rows j, cols i0..i0+3 (16B segments)
    if (tid < 64) {
        const int j = chunk * 64 + tid;
        float v0 = tile[0][tid], v1 = tile[1][tid], v2 = tile[2][tid], v3 = tile[3][tid];
        float* op = out + ((size_t)b * Nn + j) * Nn + i0;
        if (j > i0 + 3) {
            f32x4_t v; v[0] = v0; v[1] = v1; v[2] = v2; v[3] = v3;
            *(f32x4_t*)op = v;
        } else {
            if (j > i0 + 0) op[0] = v0;
            if (j > i0 + 1) op[1] = v1;
            if (j > i0 + 2) op[2] = v2;
            if (j > i0 + 3) op[3] = v3;
        }
    }
}

extern "C" void kernel_launch(void* const* d_in, const int* in_sizes, int n_in,
                              void* d_out, int out_size, void* d_ws, size_t ws_size,
                              hipStream_t stream) {
    const float* dom = (const float*)d_in[0];
    const float* evo = (const float*)d_in[1];
    const float* W1  = (const float*)d_in[2];
    const float* b1  = (const float*)d_in[3];
    const float* W2  = (const float*)d_in[4];
    const float* b2  = (const float*)d_in[5];
    const float* W3  = (const float*)d_in[6];
    const float* b3  = (const float*)d_in[7];
    float* out = (float*)d_out;

    __bf16* A16 = (__bf16*)d_ws;                         // [B][N][D] bf16 (256 KB)
    __bf16* C16 = A16 + (size_t)Bb * Nn * D;             // [B][N][D] bf16 (256 KB)
    __bf16* W2T = C16 + (size_t)Bb * Nn * D;             // [64][128] bf16 (16 KB)

    precompute_ac<<<Bb * Nn / 2, 256, 0, stream>>>(dom, evo, W1, b1, W2, A16, C16, W2T);
    coevo_main<<<Bb * 576, 256, 0, stream>>>(A16, C16, W2T, b2, W3, b3, out);
}